// Round 2
// baseline (157.273 us; speedup 1.0000x reference)
//
#include <hip/hip_runtime.h>

typedef _Float16 half_t;
typedef half_t f16x8 __attribute__((ext_vector_type(8)));
typedef float f32x4 __attribute__((ext_vector_type(4)));
typedef unsigned int u32x2 __attribute__((ext_vector_type(2)));

#define LOG2E 1.44269504088896340736f

// Problem dims (fixed)
#define NROWS 65536
#define DIN   64
#define NCTRS 1024
#define DOUT  256

// Workspace layout (bytes). ONE FRAGMENT = 64 lanes x 16 B = 1024 B.
#define CSWZ_OFF 0
#define CSWZ_BYTES (128 * 1024)
#define VSWZ_OFF (CSWZ_OFF + CSWZ_BYTES)            // 131072
#define VSWZ_BYTES (512 * 1024)
#define CSQ_OFF  (VSWZ_OFF + VSWZ_BYTES)            // 655360; end 659456

#define VT_STRIDE 260   // 256 + 4 pad
#define CT_STRIDE 68

// defer-max threshold in log2 units: p <= 2^8 = 256, safely inside f16 range
#define RESCALE_THR 8.0f

// async global->LDS, 16 B per lane, linear pattern (dest = wave-uniform base + lane*16)
#define GLOAD_LDS16(g, l)                                                      \
  __builtin_amdgcn_global_load_lds(                                            \
      (const __attribute__((address_space(1))) void*)(const void*)(g),         \
      (__attribute__((address_space(3))) void*)(void*)(l), 16, 0, 0)

// ---------------------------------------------------------------------------
// Precompute: one block per 32-center chunk. float4 global loads into LDS
// tiles, then frag-layout stores. Fragment layout (A/B symmetric):
//   lane holds [idx = lane&15][k = 8*(lane>>4) + j], j=0..7 (16 B contiguous)
// ---------------------------------------------------------------------------
__global__ __launch_bounds__(256) void precompute_kernel(
    const float* __restrict__ ctrs, const float* __restrict__ values,
    const float* __restrict__ s, char* __restrict__ ws) {
  half_t* Cswz = (half_t*)(ws + CSWZ_OFF);
  half_t* Vswz = (half_t*)(ws + VSWZ_OFF);
  float* csq2 = (float*)(ws + CSQ_OFF);

  __shared__ half_t Vt[32 * VT_STRIDE];  // 32 x 256 (padded)
  __shared__ half_t Ct[32 * CT_STRIDE];  // 32 x 64  (padded)

  const int c = blockIdx.x, tid = threadIdx.x;

  // V tile: 32x256 floats = 2048 float4, 8 per thread
#pragma unroll
  for (int i = 0; i < 8; ++i) {
    int idx = i * 256 + tid;
    int r = idx >> 6, c4 = (idx & 63) * 4;
    float4 v = ((const float4*)values)[(size_t)(c * 32 + r) * 64 + (idx & 63)];
    Vt[r * VT_STRIDE + c4 + 0] = (half_t)v.x;
    Vt[r * VT_STRIDE + c4 + 1] = (half_t)v.y;
    Vt[r * VT_STRIDE + c4 + 2] = (half_t)v.z;
    Vt[r * VT_STRIDE + c4 + 3] = (half_t)v.w;
  }
  // C tile: 32x64 floats = 512 float4, 2 per thread
#pragma unroll
  for (int i = 0; i < 2; ++i) {
    int idx = i * 256 + tid;
    int r = idx >> 4, c4 = (idx & 15) * 4;
    float4 v = ((const float4*)ctrs)[(size_t)(c * 32 + r) * 16 + (idx & 15)];
    Ct[r * CT_STRIDE + c4 + 0] = (half_t)v.x;
    Ct[r * CT_STRIDE + c4 + 1] = (half_t)v.y;
    Ct[r * CT_STRIDE + c4 + 2] = (half_t)v.z;
    Ct[r * CT_STRIDE + c4 + 3] = (half_t)v.w;
  }
  // csq2: k = tid>>3, 8 lanes each sum 8 d's, shuffle-reduce
  {
    int k = tid >> 3, dg = (tid & 7) * 8;
    const float* cp = ctrs + (size_t)(c * 32 + k) * DIN + dg;
    float acc = 0.0f;
#pragma unroll
    for (int j = 0; j < 8; ++j) acc = fmaf(cp[j] * cp[j], s[dg + j], acc);
    acc += __shfl_xor(acc, 1);
    acc += __shfl_xor(acc, 2);
    acc += __shfl_xor(acc, 4);
    if ((tid & 7) == 0) csq2[c * 32 + k] = acc * LOG2E;
  }
  __syncthreads();

  const int w = tid >> 6, l = tid & 63, l4 = l >> 4, lm = l & 15;

  {  // Cswz: frag f = w; ct = f>>1, kt = f&1
    int ct = w >> 1, kt = w & 1;
    f16x8 v;
#pragma unroll
    for (int j = 0; j < 8; ++j)
      v[j] = Ct[(ct * 16 + lm) * CT_STRIDE + kt * 32 + l4 * 8 + j];
    *(f16x8*)(Cswz + ((c * 4 + w) * 64 + l) * 8) = v;
  }
#pragma unroll
  for (int q = 0; q < 4; ++q) {  // Vswz: 16 frags, 4 per wave
    int sl = w * 4 + q;
    f16x8 v;
#pragma unroll
    for (int j = 0; j < 8; ++j)
      v[j] = Vt[(l4 * 8 + j) * VT_STRIDE + sl * 16 + lm];
    *(f16x8*)(Vswz + ((c * 16 + sl) * 64 + l) * 8) = v;
  }
}

// ---------------------------------------------------------------------------
// Fused kernel. Single-pass online softmax (defer-max), swapped operands,
// in-register P transpose (permlane), V staged in LDS.
// ROUND-2 CHANGES (vs the vmcnt(0)-lockstep version):
//   * 16 rows/wave (rt=1), 64 rows/block, grid 1024 -> half the per-wave
//     register state => 3 blocks/CU co-resident (LDS 48KB/block caps at 3).
//     1.5x more waves/SIMD to hide the per-chunk latency chain.
//   * TRIPLE-buffered V staging with COUNTED vmcnt(4): DMA(c+2) issued in
//     iter c, so the in-flight stage (chunk c+1, 4 instrs/wave) is never
//     drained -- only chunk c's DMA (older, in-order retirement) must have
//     retired at the wait. No more per-chunk full vmem drain.
// Buffer hazard audit: iter c reads buf c%3; DMA(c+1)->buf (c+1)%3 is in
// flight; DMA(c+2)->buf (c+2)%3 which was last read in iter c-1, and every
// wave crossed the iter-c barrier after that -> safe. Last 2 iters issue
// clamped dummy DMAs (src chunk 31) into dead buffers to keep counts uniform.
// ---------------------------------------------------------------------------
__global__ __launch_bounds__(256, 3) void attn_kernel(
    const float* __restrict__ x, const float* __restrict__ s,
    const char* __restrict__ ws, float* __restrict__ out) {
  const f16x8* cbase = (const f16x8*)(ws + CSWZ_OFF);
  const char* Vraw = ws + VSWZ_OFF;
  const float* csq2 = (const float*)(ws + CSQ_OFF);

  __shared__ __attribute__((aligned(16))) char vbuf[3][16384];

  const int tid = threadIdx.x;
  const int w = tid >> 6, l = tid & 63, l4 = l >> 4, lm = l & 15;
  const int rowbase = blockIdx.x * 64 + w * 16;

  // ---- DMA chunk 0 -> buf 0 (flies across the whole prologue)
#pragma unroll
  for (int i = 0; i < 4; ++i)
    GLOAD_LDS16(Vraw + i * 4096 + tid * 16, &vbuf[0][i * 4096 + w * 1024]);
  __builtin_amdgcn_sched_barrier(0);

  // ---- x*s fragments in registers (MFMA B-operand); rows = lm
  f16x8 A[2];
#pragma unroll
  for (int kt = 0; kt < 2; ++kt) {
    int din = kt * 32 + l4 * 8;
    const float* src = x + (size_t)(rowbase + lm) * DIN + din;
    f16x8 a;
#pragma unroll
    for (int j = 0; j < 8; ++j) a[j] = (half_t)(src[j] * s[din + j]);
    A[kt] = a;
  }

  // all-ones row-0 A-frag for the L (row-sum) MFMA
  f16x8 ones;
#pragma unroll
  for (int j = 0; j < 8; ++j) ones[j] = (lm == 0) ? (half_t)1.0f : (half_t)0.0f;

  __builtin_amdgcn_sched_barrier(0);
  // ---- DMA chunk 1 -> buf 1 (prologue x-loads already consumed above, so
  // the compiler's waits for them cannot drain this stage)
#pragma unroll
  for (int i = 0; i < 4; ++i)
    GLOAD_LDS16(Vraw + 16384 + i * 4096 + tid * 16,
                &vbuf[1][i * 4096 + w * 1024]);
  __builtin_amdgcn_sched_barrier(0);

  f32x4 O[16];     // O^T: lane holds [dout = u*16 + l4*4 + j][r = lm]
  f32x4 Lacc;      // row sums via ones-MFMA
  float m = -1e30f;
  Lacc = (f32x4){0.f, 0.f, 0.f, 0.f};
#pragma unroll
  for (int u = 0; u < 16; ++u) O[u] = (f32x4){0.f, 0.f, 0.f, 0.f};

  int cur = 0;  // buffer holding chunk c
#pragma unroll 1
  for (int c = 0; c < 32; ++c) {
    // counted wait: the 4 youngest vmem ops are DMA(c+1); in-order vmcnt
    // retirement => everything older (DMA(c), last iter's C/csq loads) done.
    asm volatile("s_waitcnt vmcnt(4)" ::: "memory");
    __builtin_amdgcn_s_barrier();
    __builtin_amdgcn_sched_barrier(0);

    // chunk-c C-frags + csq (global, L2-hot). Issued before the DMA so the
    // compiler's counted waits for them never drain the in-flight stage.
    f16x8 b0 = cbase[(c * 4 + 0) * 64 + l];
    f16x8 b1 = cbase[(c * 4 + 1) * 64 + l];
    f16x8 b2 = cbase[(c * 4 + 2) * 64 + l];
    f16x8 b3 = cbase[(c * 4 + 3) * 64 + l];
    f32x4 cs0 = *(const f32x4*)(csq2 + c * 32 + l4 * 4);
    f32x4 cs1 = *(const f32x4*)(csq2 + c * 32 + 16 + l4 * 4);
    __builtin_amdgcn_sched_barrier(0);

    {  // async stage chunk c+2 (clamped dummy on the last two iters)
      int cn = (c + 2 < 32) ? c + 2 : 31;
      int bn = cur + 2;
      if (bn >= 3) bn -= 3;
      const char* src = Vraw + (size_t)cn * 16384;
#pragma unroll
      for (int i = 0; i < 4; ++i)
        GLOAD_LDS16(src + i * 4096 + tid * 16, &vbuf[bn][i * 4096 + w * 1024]);
    }
    __builtin_amdgcn_sched_barrier(0);

    // ---- swapped QK^T: rows = centers (l4*4+j), cols = x-rows (lm)
    f32x4 t0 = {0.f, 0.f, 0.f, 0.f}, t1 = {0.f, 0.f, 0.f, 0.f};
    t0 = __builtin_amdgcn_mfma_f32_16x16x32_f16(b0, A[0], t0, 0, 0, 0);
    t0 = __builtin_amdgcn_mfma_f32_16x16x32_f16(b1, A[1], t0, 0, 0, 0);
    t1 = __builtin_amdgcn_mfma_f32_16x16x32_f16(b2, A[0], t1, 0, 0, 0);
    t1 = __builtin_amdgcn_mfma_f32_16x16x32_f16(b3, A[1], t1, 0, 0, 0);

    float v0[4], v1[4];
    float pm = -1e30f;
#pragma unroll
    for (int j = 0; j < 4; ++j) {
      v0[j] = fmaf(t0[j], 2.0f * LOG2E, -cs0[j]);
      v1[j] = fmaf(t1[j], 2.0f * LOG2E, -cs1[j]);
      pm = fmaxf(pm, fmaxf(v0[j], v1[j]));
    }
    // per-lane partial max -> exact row max (rows live in lm; reduce l4)
    pm = fmaxf(pm, __shfl_xor(pm, 16));
    pm = fmaxf(pm, __shfl_xor(pm, 32));

    // defer-max: rescale only when some row's max grew past THR
    if (__any(pm > m + RESCALE_THR)) {
      float mn = fmaxf(m, pm);
      float f = __builtin_amdgcn_exp2f(m - mn);  // per-lane (row lm)
      m = mn;
      Lacc *= f;
#pragma unroll
      for (int u = 0; u < 16; ++u) O[u] *= f;
    }

    // p = exp2(v - m) <= 2^THR; RTN f16 pack; permlane-route into PV B-frag
    unsigned wds[4];
#pragma unroll
    for (int h = 0; h < 2; ++h) {
      union { half_t h2[2]; unsigned u; } qa, qb;
      qa.h2[0] = (half_t)__builtin_amdgcn_exp2f(v0[2 * h] - m);
      qa.h2[1] = (half_t)__builtin_amdgcn_exp2f(v0[2 * h + 1] - m);
      qb.h2[0] = (half_t)__builtin_amdgcn_exp2f(v1[2 * h] - m);
      qb.h2[1] = (half_t)__builtin_amdgcn_exp2f(v1[2 * h + 1] - m);
      u32x2 sw1 = __builtin_amdgcn_permlane32_swap(qa.u, qb.u, false, false);
      u32x2 sw2 = __builtin_amdgcn_permlane16_swap(sw1.x, sw1.y, false, false);
      wds[h] = sw2.x;       // word h   : elements 2h,2h+1
      wds[h + 2] = sw2.y;   // word h+2 : elements 2h+4,2h+5
    }
    union { unsigned u[4]; f16x8 v; } pk;
    pk.u[0] = wds[0]; pk.u[1] = wds[1]; pk.u[2] = wds[2]; pk.u[3] = wds[3];
    f16x8 pb = pk.v;

    // ---- PV (swapped): O^T += V^T * P^T ; V frags from staged LDS
    const char* vb = &vbuf[cur][l * 16];
#pragma unroll
    for (int u = 0; u < 16; ++u) {
      f16x8 vf = *(const f16x8*)(vb + u * 1024);
      O[u] = __builtin_amdgcn_mfma_f32_16x16x32_f16(vf, pb, O[u], 0, 0, 0);
    }
    Lacc = __builtin_amdgcn_mfma_f32_16x16x32_f16(ones, pb, Lacc, 0, 0, 0);

    cur = (cur == 2) ? 0 : cur + 1;
  }

  // ---- epilogue: L row-sum lives at D[0][r]: lane r (0..15), reg 0.
  // O^T layout -> 4 consecutive douts per lane: contiguous dwordx4 stores.
  {
    float lv = __shfl(Lacc[0], lm);
    float inv = 1.0f / fmaxf(lv, 1e-30f);
    float* po = out + (size_t)(rowbase + lm) * DOUT + l4 * 4;
#pragma unroll
    for (int u = 0; u < 16; ++u) {
      f32x4 ov = O[u] * inv;
      *(f32x4*)(po + u * 16) = ov;
    }
  }
}

extern "C" void kernel_launch(void* const* d_in, const int* in_sizes, int n_in,
                              void* d_out, int out_size, void* d_ws, size_t ws_size,
                              hipStream_t stream) {
  const float* x = (const float*)d_in[0];
  const float* ctrs = (const float*)d_in[1];
  const float* values = (const float*)d_in[2];
  const float* s = (const float*)d_in[3];
  float* out = (float*)d_out;
  char* ws = (char*)d_ws;

  hipLaunchKernelGGL(precompute_kernel, dim3(32), dim3(256), 0, stream,
                     ctrs, values, s, ws);
  hipLaunchKernelGGL(attn_kernel, dim3(1024), dim3(256), 0, stream,
                     x, s, ws, out);
}

// Round 3
// 141.093 us; speedup vs baseline: 1.1147x; 1.1147x over previous
//
#include <hip/hip_runtime.h>

typedef _Float16 half_t;
typedef half_t f16x8 __attribute__((ext_vector_type(8)));
typedef float f32x4 __attribute__((ext_vector_type(4)));
typedef unsigned int u32x2 __attribute__((ext_vector_type(2)));

#define LOG2E 1.44269504088896340736f

// Problem dims (fixed)
#define NROWS 65536
#define DIN   64
#define NCTRS 1024
#define DOUT  256

// Workspace layout (bytes). ONE FRAGMENT = 64 lanes x 16 B = 1024 B.
#define CSWZ_OFF 0
#define CSWZ_BYTES (128 * 1024)
#define VSWZ_OFF (CSWZ_OFF + CSWZ_BYTES)            // 131072
#define VSWZ_BYTES (512 * 1024)
#define CSQ_OFF  (VSWZ_OFF + VSWZ_BYTES)            // 655360; end 659456

#define CT_STRIDE 68

// defer-max threshold in log2 units: p <= 2^8 = 256, safely inside f16 range
#define RESCALE_THR 8.0f

// async global->LDS, 16 B per lane, linear pattern (dest = wave-uniform base + lane*16)
#define GLOAD_LDS16(g, l)                                                      \
  __builtin_amdgcn_global_load_lds(                                            \
      (const __attribute__((address_space(1))) void*)(const void*)(g),         \
      (__attribute__((address_space(3))) void*)(void*)(l), 16, 0, 0)

// ---------------------------------------------------------------------------
// Precompute, 256 blocks: bid = part(3b)*32 + c? -> c = bid & 31, part = bid>>5.
// Each block converts a 32x32 slice of V for chunk c (douts part*32..+31) into
// 2 Vswz frags. part==0 blocks additionally do Cswz + csq for chunk c.
// Fragment layout (A/B symmetric): lane holds [idx=lane&15][k=8*(lane>>4)+j].
// ---------------------------------------------------------------------------
__global__ __launch_bounds__(256) void precompute_kernel(
    const float* __restrict__ ctrs, const float* __restrict__ values,
    const float* __restrict__ s, char* __restrict__ ws) {
  half_t* Cswz = (half_t*)(ws + CSWZ_OFF);
  half_t* Vswz = (half_t*)(ws + VSWZ_OFF);
  float* csq2 = (float*)(ws + CSQ_OFF);

  __shared__ half_t Vt[32 * 36];         // 32 x 32 (+4 pad)
  __shared__ half_t Ct[32 * CT_STRIDE];  // 32 x 64 (padded)

  const int bid = blockIdx.x, tid = threadIdx.x;
  const int c = bid & 31, part = bid >> 5;
  const int w = tid >> 6, l = tid & 63, l4 = l >> 4, lm = l & 15;

  {  // V subtile: rows c*32..+31, douts part*32..+31 -> 256 float4 (1/thread)
    int r = tid >> 3, f4 = tid & 7;
    float4 v = ((const float4*)values)[(size_t)(c * 32 + r) * 64 + part * 8 + f4];
    half_t* d = Vt + r * 36 + f4 * 4;
    d[0] = (half_t)v.x; d[1] = (half_t)v.y;
    d[2] = (half_t)v.z; d[3] = (half_t)v.w;
  }
  if (part == 0) {
    // C tile: 32x64 floats = 512 float4, 2 per thread
#pragma unroll
    for (int i = 0; i < 2; ++i) {
      int idx = i * 256 + tid;
      int r = idx >> 4, c4 = (idx & 15) * 4;
      float4 v = ((const float4*)ctrs)[(size_t)(c * 32 + r) * 16 + (idx & 15)];
      Ct[r * CT_STRIDE + c4 + 0] = (half_t)v.x;
      Ct[r * CT_STRIDE + c4 + 1] = (half_t)v.y;
      Ct[r * CT_STRIDE + c4 + 2] = (half_t)v.z;
      Ct[r * CT_STRIDE + c4 + 3] = (half_t)v.w;
    }
    // csq2: k = tid>>3, 8 lanes each sum 8 d's, shuffle-reduce
    {
      int k = tid >> 3, dg = (tid & 7) * 8;
      const float* cp = ctrs + (size_t)(c * 32 + k) * DIN + dg;
      float acc = 0.0f;
#pragma unroll
      for (int j = 0; j < 8; ++j) acc = fmaf(cp[j] * cp[j], s[dg + j], acc);
      acc += __shfl_xor(acc, 1);
      acc += __shfl_xor(acc, 2);
      acc += __shfl_xor(acc, 4);
      if ((tid & 7) == 0) csq2[c * 32 + k] = acc * LOG2E;
    }
  }
  __syncthreads();

  if (w < 2) {  // 2 Vswz frags per block: sl = part*2 + w
    int sl = part * 2 + w;
    f16x8 v;
#pragma unroll
    for (int j = 0; j < 8; ++j) v[j] = Vt[(l4 * 8 + j) * 36 + w * 16 + lm];
    *(f16x8*)(Vswz + ((c * 16 + sl) * 64 + l) * 8) = v;
  }
  if (part == 0) {  // Cswz: frag f = w; ct = f>>1, kt = f&1
    int ct = w >> 1, kt = w & 1;
    f16x8 v;
#pragma unroll
    for (int j = 0; j < 8; ++j)
      v[j] = Ct[(ct * 16 + lm) * CT_STRIDE + kt * 32 + l4 * 8 + j];
    *(f16x8*)(Cswz + ((c * 4 + w) * 64 + l) * 8) = v;
  }
}

// ---------------------------------------------------------------------------
// Fused kernel, CROSS-CHUNK SOFTWARE PIPELINE.
// Geometry: 32 rows/wave (rt=2), 128 rows/block, grid 512 (2 blocks/CU).
// Per iteration c:  softmax(c) [t from QK issued in iter c-1]
//                -> QK(c+1)    [C-frags from LDS, DMA'd at iter c-2]
//                -> PV(c)      [V from LDS, DMA'd at iter c-2]
// All operands staged via global_load_lds with counted vmcnt (never 0):
//   per-iter vmem = V-DMA(c+2) 4 ops + C-DMA(c+3) 1 op = 5.
//   top-of-iter vmcnt(5) retires V(c) and C(c+1), leaves [V(c+1),C(c+2)].
// The serial chain load->QK->softmax->PV is thus split across 3 iterations:
// no consumer waits on a fresh producer within an iteration.
// LDS: V 3x16KB + C 4x4KB + csq 4KB = 68 KB -> 2 blocks/CU.
// ---------------------------------------------------------------------------
__global__ __launch_bounds__(256, 2) void attn_kernel(
    const float* __restrict__ x, const float* __restrict__ s,
    const char* __restrict__ ws, float* __restrict__ out) {
  const char* Craw = ws + CSWZ_OFF;
  const char* Vraw = ws + VSWZ_OFF;
  const char* csqg = ws + CSQ_OFF;

  __shared__ __attribute__((aligned(16))) char vbuf[3][16384];
  __shared__ __attribute__((aligned(16))) char cbuf[4][4096];
  __shared__ __attribute__((aligned(16))) float csq_l[1024];

  const int tid = threadIdx.x;
  const int w = tid >> 6, l = tid & 63, l4 = l >> 4, lm = l & 15;
  const int rowbase = blockIdx.x * 128 + w * 32;

#define STAGE_V(chunk, bufidx)                                                 \
  do {                                                                         \
    const char* _s = Vraw + (size_t)(chunk) * 16384;                           \
    char* _d = vbuf[bufidx];                                                   \
    _Pragma("unroll") for (int _i = 0; _i < 4; ++_i)                           \
        GLOAD_LDS16(_s + _i * 4096 + tid * 16, _d + _i * 4096 + w * 1024);     \
  } while (0)
#define STAGE_C(chunk, bufidx)                                                 \
  GLOAD_LDS16(Craw + (size_t)(chunk) * 4096 + tid * 16,                        \
              (char*)cbuf[bufidx] + w * 1024)

  // ---- prologue DMAs: V(0), C(0), C(1), csq (whole table)
  STAGE_V(0, 0);
  STAGE_C(0, 0);
  STAGE_C(1, 1);
  GLOAD_LDS16(csqg + tid * 16, (char*)csq_l + w * 1024);
  __builtin_amdgcn_sched_barrier(0);

  // ---- x*s fragments (MFMA B-operand). Consuming x drains all older vmem
  // (the prologue DMAs) via the compiler's waitcnt -> LDS ready pre-barrier.
  f16x8 A[2][2];
#pragma unroll
  for (int rt = 0; rt < 2; ++rt) {
#pragma unroll
    for (int kt = 0; kt < 2; ++kt) {
      int din = kt * 32 + l4 * 8;
      const float* src = x + (size_t)(rowbase + rt * 16 + lm) * DIN + din;
      f16x8 a;
#pragma unroll
      for (int j = 0; j < 8; ++j) a[j] = (half_t)(src[j] * s[din + j]);
      A[rt][kt] = a;
    }
  }

  // all-ones row-0 A-frag for the L (row-sum) MFMA
  f16x8 ones;
#pragma unroll
  for (int j = 0; j < 8; ++j) ones[j] = (lm == 0) ? (half_t)1.0f : (half_t)0.0f;

  __syncthreads();  // all waves' prologue DMAs retired -> C(0)/csq visible

  // ---- QK(0) -> t (pipeline prime)
  f32x4 t[2][2];
  {
    const char* cb = cbuf[0];
    f16x8 b0 = *(const f16x8*)(cb + 0 * 1024 + l * 16);
    f16x8 b1 = *(const f16x8*)(cb + 1 * 1024 + l * 16);
    f16x8 b2 = *(const f16x8*)(cb + 2 * 1024 + l * 16);
    f16x8 b3 = *(const f16x8*)(cb + 3 * 1024 + l * 16);
#pragma unroll
    for (int rt = 0; rt < 2; ++rt) {
      f32x4 a0 = {0.f, 0.f, 0.f, 0.f}, a1 = {0.f, 0.f, 0.f, 0.f};
      a0 = __builtin_amdgcn_mfma_f32_16x16x32_f16(b0, A[rt][0], a0, 0, 0, 0);
      a0 = __builtin_amdgcn_mfma_f32_16x16x32_f16(b1, A[rt][1], a0, 0, 0, 0);
      a1 = __builtin_amdgcn_mfma_f32_16x16x32_f16(b2, A[rt][0], a1, 0, 0, 0);
      a1 = __builtin_amdgcn_mfma_f32_16x16x32_f16(b3, A[rt][1], a1, 0, 0, 0);
      t[rt][0] = a0;
      t[rt][1] = a1;
    }
  }
  __builtin_amdgcn_sched_barrier(0);
  STAGE_V(1, 1);
  STAGE_C(2, 2);
  __builtin_amdgcn_sched_barrier(0);

  f32x4 O[2][16];  // O^T: lane holds [dout = u*16 + l4*4 + reg][r = lm]
  f32x4 Lacc[2];
  float m[2] = {-1e30f, -1e30f};
#pragma unroll
  for (int rt = 0; rt < 2; ++rt) {
    Lacc[rt] = (f32x4){0.f, 0.f, 0.f, 0.f};
#pragma unroll
    for (int u = 0; u < 16; ++u) O[rt][u] = (f32x4){0.f, 0.f, 0.f, 0.f};
  }

  int vcur = 0;  // = c % 3
#pragma unroll 1
  for (int c = 0; c < 32; ++c) {
    // retire V(c) + C(c+1); leave [V(c+1) 4, C(c+2) 1] in flight
    asm volatile("s_waitcnt vmcnt(5)" ::: "memory");
    __builtin_amdgcn_s_barrier();
    __builtin_amdgcn_sched_barrier(0);

    {  // issue next stage: V(c+2), C(c+3) (clamped dummies into dead buffers)
      int vn = (c + 2 < 32) ? c + 2 : 31;
      int cn = (c + 3 < 32) ? c + 3 : 31;
      int vnb = vcur + 2;
      if (vnb >= 3) vnb -= 3;
      STAGE_V(vn, vnb);
      STAGE_C(cn, (c + 3) & 3);
    }
    __builtin_amdgcn_sched_barrier(0);

    // early issue: C-frags for QK(c+1) (consumed ~softmax-length later)
    const char* cb = cbuf[(c + 1) & 3];
    f16x8 b0 = *(const f16x8*)(cb + 0 * 1024 + l * 16);
    f16x8 b1 = *(const f16x8*)(cb + 1 * 1024 + l * 16);
    f16x8 b2 = *(const f16x8*)(cb + 2 * 1024 + l * 16);
    f16x8 b3 = *(const f16x8*)(cb + 3 * 1024 + l * 16);
    f32x4 cs0 = *(const f32x4*)&csq_l[c * 32 + l4 * 4];
    f32x4 cs1 = *(const f32x4*)&csq_l[c * 32 + 16 + l4 * 4];

    // ---- softmax(c): t was computed last iteration; no waits here
    f16x8 pb[2];
#pragma unroll
    for (int rt = 0; rt < 2; ++rt) {
      float v0[4], v1[4];
#pragma unroll
      for (int j = 0; j < 4; ++j) {
        v0[j] = fmaf(t[rt][0][j], 2.0f * LOG2E, -cs0[j]);
        v1[j] = fmaf(t[rt][1][j], 2.0f * LOG2E, -cs1[j]);
      }
      float pm = fmaxf(fmaxf(fmaxf(v0[0], v0[1]), fmaxf(v0[2], v0[3])),
                       fmaxf(fmaxf(v1[0], v1[1]), fmaxf(v1[2], v1[3])));
      pm = fmaxf(pm, __shfl_xor(pm, 16));
      pm = fmaxf(pm, __shfl_xor(pm, 32));

      if (__any(pm > m[rt] + RESCALE_THR)) {
        float mn = fmaxf(m[rt], pm);
        float f = __builtin_amdgcn_exp2f(m[rt] - mn);  // per-lane (row lm)
        m[rt] = mn;
        Lacc[rt] *= f;
#pragma unroll
        for (int u = 0; u < 16; ++u) O[rt][u] *= f;
      }

      unsigned wds[4];
#pragma unroll
      for (int h = 0; h < 2; ++h) {
        union { half_t h2[2]; unsigned u; } qa, qb;
        qa.h2[0] = (half_t)__builtin_amdgcn_exp2f(v0[2 * h] - m[rt]);
        qa.h2[1] = (half_t)__builtin_amdgcn_exp2f(v0[2 * h + 1] - m[rt]);
        qb.h2[0] = (half_t)__builtin_amdgcn_exp2f(v1[2 * h] - m[rt]);
        qb.h2[1] = (half_t)__builtin_amdgcn_exp2f(v1[2 * h + 1] - m[rt]);
        u32x2 sw1 = __builtin_amdgcn_permlane32_swap(qa.u, qb.u, false, false);
        u32x2 sw2 = __builtin_amdgcn_permlane16_swap(sw1.x, sw1.y, false, false);
        wds[h] = sw2.x;
        wds[h + 2] = sw2.y;
      }
      union { unsigned u[4]; f16x8 v; } pk;
      pk.u[0] = wds[0]; pk.u[1] = wds[1]; pk.u[2] = wds[2]; pk.u[3] = wds[3];
      pb[rt] = pk.v;
    }

    // ---- QK(c+1) -> t (overwrite; consumed next iteration). c=31: clamped
    // recompute of chunk 31 (cbuf[0] holds chunk-31 data then), unused.
#pragma unroll
    for (int rt = 0; rt < 2; ++rt) {
      f32x4 a0 = {0.f, 0.f, 0.f, 0.f}, a1 = {0.f, 0.f, 0.f, 0.f};
      a0 = __builtin_amdgcn_mfma_f32_16x16x32_f16(b0, A[rt][0], a0, 0, 0, 0);
      a0 = __builtin_amdgcn_mfma_f32_16x16x32_f16(b1, A[rt][1], a0, 0, 0, 0);
      a1 = __builtin_amdgcn_mfma_f32_16x16x32_f16(b2, A[rt][0], a1, 0, 0, 0);
      a1 = __builtin_amdgcn_mfma_f32_16x16x32_f16(b3, A[rt][1], a1, 0, 0, 0);
      t[rt][0] = a0;
      t[rt][1] = a1;
    }

    // ---- PV(c): O^T += V^T * P^T ; V frags from staged LDS
    __builtin_amdgcn_s_setprio(1);
    const char* vb = &vbuf[vcur][l * 16];
#pragma unroll
    for (int u = 0; u < 16; ++u) {
      f16x8 vf = *(const f16x8*)(vb + u * 1024);
      O[0][u] = __builtin_amdgcn_mfma_f32_16x16x32_f16(vf, pb[0], O[0][u], 0, 0, 0);
      O[1][u] = __builtin_amdgcn_mfma_f32_16x16x32_f16(vf, pb[1], O[1][u], 0, 0, 0);
    }
    Lacc[0] = __builtin_amdgcn_mfma_f32_16x16x32_f16(ones, pb[0], Lacc[0], 0, 0, 0);
    Lacc[1] = __builtin_amdgcn_mfma_f32_16x16x32_f16(ones, pb[1], Lacc[1], 0, 0, 0);
    __builtin_amdgcn_s_setprio(0);

    vcur = (vcur == 2) ? 0 : vcur + 1;
  }

  // ---- epilogue: L row-sum = D[0][r] of ones-MFMA: lane r (0..15), reg 0.
  // O^T layout -> 4 consecutive douts per lane: contiguous dwordx4 stores.
#pragma unroll
  for (int rt = 0; rt < 2; ++rt) {
    float lv = __shfl(Lacc[rt][0], lm);
    float inv = 1.0f / fmaxf(lv, 1e-30f);
    float* po = out + (size_t)(rowbase + rt * 16 + lm) * DOUT + l4 * 4;
#pragma unroll
    for (int u = 0; u < 16; ++u) {
      f32x4 ov = O[rt][u] * inv;
      *(f32x4*)(po + u * 16) = ov;
    }
  }
#undef STAGE_V
#undef STAGE_C
}

extern "C" void kernel_launch(void* const* d_in, const int* in_sizes, int n_in,
                              void* d_out, int out_size, void* d_ws, size_t ws_size,
                              hipStream_t stream) {
  const float* x = (const float*)d_in[0];
  const float* ctrs = (const float*)d_in[1];
  const float* values = (const float*)d_in[2];
  const float* s = (const float*)d_in[3];
  float* out = (float*)d_out;
  char* ws = (char*)d_ws;

  hipLaunchKernelGGL(precompute_kernel, dim3(256), dim3(256), 0, stream,
                     ctrs, values, s, ws);
  hipLaunchKernelGGL(attn_kernel, dim3(512), dim3(256), 0, stream,
                     x, s, ws, out);
}